// Round 8
// baseline (375.427 us; speedup 1.0000x reference)
//
#include <hip/hip_runtime.h>
#include <math.h>

#define D_MODEL 1024
#define NH 16
#define DK 64
#define S_LEN 1024
#define BATCH 4
#define MROWS (BATCH * S_LEN)  // 4096

typedef short bf16x8 __attribute__((ext_vector_type(8)));
typedef float f32x4 __attribute__((ext_vector_type(4)));
typedef unsigned short u16;

__device__ __forceinline__ float elu1(float x) {
    return x > 0.f ? x : (expf(x) - 1.f);
}

__device__ __forceinline__ u16 f2bf(float f) {
    union { float f; unsigned u; } v; v.f = f;
    unsigned u = v.u;
    return (u16)((u + 0x7fffu + ((u >> 16) & 1u)) >> 16);
}

__device__ __forceinline__ unsigned pack2(float a, float b) {
    union { float f; unsigned u; } ua, ub; ua.f = a; ub.f = b;
    return ((ua.u + 0x8000u) >> 16) | ((ub.u + 0x8000u) & 0xffff0000u);
}

// ---------------------------------------------------------------------------
// cast_wt: W f32 [k][n] -> WT bf16 [n][k], for the 4 d_model x d_model weights.
__global__ __launch_bounds__(256) void cast_wt(
    const float* __restrict__ wq, const float* __restrict__ wk,
    const float* __restrict__ wv, const float* __restrict__ wo,
    u16* __restrict__ WT)
{
    __shared__ float T[64][65];
    const int z = blockIdx.z;
    const float* W = (z == 0) ? wq : ((z == 1) ? wk : ((z == 2) ? wv : wo));
    u16* O = WT + (size_t)z * D_MODEL * D_MODEL;
    const int tid = threadIdx.x;
    const int k0 = blockIdx.y * 64, n0 = blockIdx.x * 64;
    const int r = tid >> 4, c4 = (tid & 15) * 4;
    #pragma unroll
    for (int p = 0; p < 4; p++) {
        float4 v = *(const float4*)&W[(size_t)(k0 + r + p * 16) * D_MODEL + n0 + c4];
        T[r + p * 16][c4 + 0] = v.x; T[r + p * 16][c4 + 1] = v.y;
        T[r + p * 16][c4 + 2] = v.z; T[r + p * 16][c4 + 3] = v.w;
    }
    __syncthreads();
    #pragma unroll
    for (int p = 0; p < 4; p++) {
        const int i = r + p * 16;
        ushort4 o4;
        o4.x = f2bf(T[c4 + 0][i]); o4.y = f2bf(T[c4 + 1][i]);
        o4.z = f2bf(T[c4 + 2][i]); o4.w = f2bf(T[c4 + 3][i]);
        *(ushort4*)&O[(size_t)(n0 + i) * D_MODEL + k0 + c4] = o4;
    }
}

// ---------------------------------------------------------------------------
// proj_fused: phase 1 = 128x128 tile of X(f32) @ W1^T(bf16) + b1, BK=64 as two
// 32-k panels; BOTH operands register-prefetched (global loads issued right
// after the barrier so the barrier never drains them). Phase 2 = per-head
// 64x64 linear + aux. Grid (32,8,3): XCD = bx%8 -> row-group stays on one XCD.
__global__ __launch_bounds__(256) void proj_fused(
    const float* __restrict__ Xq, const float* __restrict__ Xk, const float* __restrict__ Xv,
    const u16* __restrict__ WTq, const u16* __restrict__ WTk, const u16* __restrict__ WTv,
    const float* __restrict__ bq, const float* __restrict__ bk, const float* __restrict__ bv,
    const float* __restrict__ spatial_w, const float* __restrict__ spatial_b,
    const float* __restrict__ qproj_w, const float* __restrict__ qproj_b,
    const float* __restrict__ kproj_w, const float* __restrict__ kproj_b,
    const float* __restrict__ vlin_w, const float* __restrict__ vlin_b,
    const float* __restrict__ chan_w, const float* __restrict__ chan_b,
    u16* __restrict__ Qh, u16* __restrict__ K2, u16* __restrict__ V2t,
    float* __restrict__ mB, float* __restrict__ uB, float* __restrict__ vB)
{
    // phase 1: As = smem[0..8191] (2 panels x [128][32]), Bs = smem[8192..16383]
    // phase 2: Pw[4] = smem + wave*4608 ([64][72]); W2t = smem + 18432 ([64][72])
    __shared__ __align__(16) u16 smem[23040];
    __shared__ float auxA[64];
    __shared__ float auxS;

    u16* As = smem;
    u16* Bs = smem + 8192;
    u16* W2t = smem + 18432;

    const int z = blockIdx.z;
    const float* X = (z == 0) ? Xq : ((z == 1) ? Xk : Xv);
    const u16* WT = (z == 0) ? WTq : ((z == 1) ? WTk : WTv);
    const float* B1 = (z == 0) ? bq : ((z == 1) ? bk : bv);
    const float* W2 = (z == 0) ? spatial_w : ((z == 1) ? kproj_w : vlin_w);
    const float* B2 = (z == 0) ? spatial_b : ((z == 1) ? kproj_b : vlin_b);

    const int tid = threadIdx.x;
    const int wave = tid >> 6, lane = tid & 63;
    const int col = lane & 15, quad = lane >> 4;
    const int wr = wave >> 1, wc = wave & 1;
    const int r0 = blockIdx.x * 128, n0 = blockIdx.y * 128;
    const int hh = blockIdx.y * 2 + wc;  // head this wave owns

    // ---- stage W2t (transposed bf16) + aux before phase 1 ----
    #pragma unroll
    for (int p = 0; p < 4; p++) {
        int idx = p * 256 + tid;
        int f = idx >> 4, e4 = (idx & 15) * 4;
        float4 w4 = *(const float4*)&W2[f * 64 + e4];
        W2t[(e4 + 0) * 72 + f] = f2bf(w4.x);
        W2t[(e4 + 1) * 72 + f] = f2bf(w4.y);
        W2t[(e4 + 2) * 72 + f] = f2bf(w4.z);
        W2t[(e4 + 3) * 72 + f] = f2bf(w4.w);
    }
    if (z == 0) {
        {
            int row = tid >> 2, part = tid & 3;
            float s = 0.f;
            for (int e = part * 16; e < part * 16 + 16; e++) s += qproj_w[row * 64 + e];
            s += __shfl_xor(s, 1);
            s += __shfl_xor(s, 2);
            if (part == 0) auxA[row] = s * (1.f / 64.f);
        }
        if (tid < 64) {
            float s = qproj_b[tid];
            #pragma unroll
            for (int m = 1; m < 64; m <<= 1) s += __shfl_xor(s, m);
            if (tid == 0) auxS = s * (1.f / 64.f);
        }
    }

    // ---- phase 1: big GEMM, BK=64 (two 32-k panels), register-prefetch ----
    // A: thread -> row = tid>>1, panel = tid&1 (32 f32 -> 32 bf16 per iter)
    const int arow = tid >> 1, ap = tid & 1;
    const float* aptr = X + (size_t)(r0 + arow) * D_MODEL + ap * 32;
    u16* adst = As + ap * 4096 + arow * 32;

    // B: thread -> row = tid>>1, panel = tid&1 (32 u16 per iter)
    const u16* bsrc = WT + (size_t)(n0 + arow) * D_MODEL + ap * 32;
    u16* bdst = Bs + ap * 4096 + arow * 32;

    f32x4 acc[4][4];
    #pragma unroll
    for (int i = 0; i < 4; i++)
        #pragma unroll
        for (int j = 0; j < 4; j++)
            acc[i][j] = (f32x4){0.f, 0.f, 0.f, 0.f};

    float4 fr[8];
    uint4 bu[4];
    #pragma unroll
    for (int i = 0; i < 8; i++) fr[i] = *(const float4*)(aptr + i * 4);
    #pragma unroll
    for (int i = 0; i < 4; i++) bu[i] = *(const uint4*)(bsrc + i * 8);

    for (int k0 = 0; k0 < D_MODEL; k0 += 64) {
        if (k0) __syncthreads();  // waves done reading LDS for prev iter
        // drain prefetched regs into LDS (pack A to bf16 on the fly)
        #pragma unroll
        for (int j = 0; j < 4; j++) {
            uint4 q;
            q.x = pack2(fr[2 * j].x, fr[2 * j].y);
            q.y = pack2(fr[2 * j].z, fr[2 * j].w);
            q.z = pack2(fr[2 * j + 1].x, fr[2 * j + 1].y);
            q.w = pack2(fr[2 * j + 1].z, fr[2 * j + 1].w);
            *(uint4*)(adst + j * 8) = q;
        }
        #pragma unroll
        for (int i = 0; i < 4; i++) *(uint4*)(bdst + i * 8) = bu[i];
        __syncthreads();  // only ds_writes to drain; prefetch loads not in flight

        // issue next tile's global loads AFTER the barrier
        if (k0 + 64 < D_MODEL) {
            const float* apn = aptr + k0 + 64;
            #pragma unroll
            for (int i = 0; i < 8; i++) fr[i] = *(const float4*)(apn + i * 4);
            const u16* bpn = bsrc + k0 + 64;
            #pragma unroll
            for (int i = 0; i < 4; i++) bu[i] = *(const uint4*)(bpn + i * 8);
        }

        const u16* Abase = As + (wr * 64 + col) * 32 + quad * 8;
        const u16* Bbase = Bs + (wc * 64 + col) * 32 + quad * 8;
        #pragma unroll
        for (int p = 0; p < 2; p++) {
            bf16x8 af[4], bfr[4];
            #pragma unroll
            for (int mi = 0; mi < 4; mi++) af[mi] = *(const bf16x8*)(Abase + p * 4096 + mi * 512);
            #pragma unroll
            for (int ni = 0; ni < 4; ni++) bfr[ni] = *(const bf16x8*)(Bbase + p * 4096 + ni * 512);
            #pragma unroll
            for (int mi = 0; mi < 4; mi++)
                #pragma unroll
                for (int ni = 0; ni < 4; ni++)
                    acc[mi][ni] = __builtin_amdgcn_mfma_f32_16x16x32_bf16(af[mi], bfr[ni], acc[mi][ni], 0, 0, 0);
        }
    }

    // ---- phase 2: epilogue ----
    float b1v[4];
    #pragma unroll
    for (int ni = 0; ni < 4; ni++) b1v[ni] = B1[hh * 64 + ni * 16 + col];

    const int rbase = r0 + wr * 64;
    const int b = rbase >> 10;
    const int s0 = rbase & 1023;
    const size_t svecbase = ((size_t)b * NH + hh) * S_LEN;

    if (z == 1) {
        float cw[4], cb[4];
        #pragma unroll
        for (int ni = 0; ni < 4; ni++) { cw[ni] = chan_w[ni * 16 + col]; cb[ni] = chan_b[ni * 16 + col]; }
        #pragma unroll
        for (int mi = 0; mi < 4; mi++)
            #pragma unroll
            for (int r = 0; r < 4; r++) {
                float su = 0.f, sv = 0.f;
                #pragma unroll
                for (int ni = 0; ni < 4; ni++) {
                    float p = acc[mi][ni][r] + b1v[ni];
                    su += p * cw[ni];
                    sv += p * cb[ni];
                }
                su += __shfl_xor(su, 1); su += __shfl_xor(su, 2);
                su += __shfl_xor(su, 4); su += __shfl_xor(su, 8);
                sv += __shfl_xor(sv, 1); sv += __shfl_xor(sv, 2);
                sv += __shfl_xor(sv, 4); sv += __shfl_xor(sv, 8);
                if (col == 0) {
                    const size_t idx = svecbase + s0 + mi * 16 + quad * 4 + r;
                    uB[idx] = su;
                    vB[idx] = sv;
                }
            }
    }

    __syncthreads();  // all phase-1 As/Bs reads done; safe to alias Pw over them

    u16* Pw = smem + wave * 4608;
    #pragma unroll
    for (int mi = 0; mi < 4; mi++)
        #pragma unroll
        for (int ni = 0; ni < 4; ni++)
            #pragma unroll
            for (int r = 0; r < 4; r++)
                Pw[(mi * 16 + quad * 4 + r) * 72 + ni * 16 + col] =
                    f2bf(acc[mi][ni][r] + b1v[ni]);

    __builtin_amdgcn_s_waitcnt(0xc07f);  // lgkmcnt(0), wave-local visibility

    bf16x8 af2[4][2], bf2r[4][2];
    #pragma unroll
    for (int mi = 0; mi < 4; mi++) {
        af2[mi][0] = *(const bf16x8*)&Pw[(mi * 16 + col) * 72 + quad * 8];
        af2[mi][1] = *(const bf16x8*)&Pw[(mi * 16 + col) * 72 + 32 + quad * 8];
    }
    #pragma unroll
    for (int ni = 0; ni < 4; ni++) {
        bf2r[ni][0] = *(const bf16x8*)&W2t[(ni * 16 + col) * 72 + quad * 8];
        bf2r[ni][1] = *(const bf16x8*)&W2t[(ni * 16 + col) * 72 + 32 + quad * 8];
    }
    f32x4 out2[4][4];
    #pragma unroll
    for (int mi = 0; mi < 4; mi++)
        #pragma unroll
        for (int ni = 0; ni < 4; ni++) {
            f32x4 c = (f32x4){0.f, 0.f, 0.f, 0.f};
            c = __builtin_amdgcn_mfma_f32_16x16x32_bf16(af2[mi][0], bf2r[ni][0], c, 0, 0, 0);
            c = __builtin_amdgcn_mfma_f32_16x16x32_bf16(af2[mi][1], bf2r[ni][1], c, 0, 0, 0);
            out2[mi][ni] = c;
        }

    float b2v[4];
    #pragma unroll
    for (int ni = 0; ni < 4; ni++) b2v[ni] = B2[ni * 16 + col];
    float qs[4][4][4];
    #pragma unroll
    for (int mi = 0; mi < 4; mi++)
        #pragma unroll
        for (int ni = 0; ni < 4; ni++)
            #pragma unroll
            for (int r = 0; r < 4; r++)
                qs[mi][ni][r] = elu1(out2[mi][ni][r] + b2v[ni]);

    if (z == 0) {
        float aw[4];
        #pragma unroll
        for (int ni = 0; ni < 4; ni++) aw[ni] = auxA[ni * 16 + col];
        #pragma unroll
        for (int mi = 0; mi < 4; mi++)
            #pragma unroll
            for (int r = 0; r < 4; r++) {
                float pm = 0.f;
                #pragma unroll
                for (int ni = 0; ni < 4; ni++) pm += qs[mi][ni][r] * aw[ni];
                pm += __shfl_xor(pm, 1); pm += __shfl_xor(pm, 2);
                pm += __shfl_xor(pm, 4); pm += __shfl_xor(pm, 8);
                if (col == 0)
                    mB[svecbase + s0 + mi * 16 + quad * 4 + r] = pm + auxS;
            }
        #pragma unroll
        for (int mi = 0; mi < 4; mi++)
            #pragma unroll
            for (int ni = 0; ni < 4; ni++)
                #pragma unroll
                for (int r = 0; r < 4; r++)
                    Qh[(size_t)(rbase + mi * 16 + quad * 4 + r) * D_MODEL
                       + hh * 64 + ni * 16 + col] = f2bf(qs[mi][ni][r] * 0.125f);
    } else if (z == 1) {
        #pragma unroll
        for (int mi = 0; mi < 4; mi++)
            #pragma unroll
            for (int ni = 0; ni < 4; ni++)
                #pragma unroll
                for (int r = 0; r < 4; r++)
                    K2[(size_t)(rbase + mi * 16 + quad * 4 + r) * D_MODEL
                       + hh * 64 + ni * 16 + col] = f2bf(qs[mi][ni][r]);
    } else {
        __builtin_amdgcn_s_waitcnt(0xc07f);  // A-frag reads done before overwrite
        #pragma unroll
        for (int mi = 0; mi < 4; mi++)
            #pragma unroll
            for (int ni = 0; ni < 4; ni++)
                #pragma unroll
                for (int r = 0; r < 4; r++)
                    Pw[(ni * 16 + col) * 72 + mi * 16 + quad * 4 + r] = f2bf(qs[mi][ni][r]);
        __builtin_amdgcn_s_waitcnt(0xc07f);
        const int d = lane;
        u16* dst = V2t + (((size_t)b * NH + hh) * DK + d) * S_LEN + s0;
        const u16* srcp = Pw + d * 72;
        #pragma unroll
        for (int seg = 0; seg < 8; seg++)
            *(uint4*)(dst + seg * 8) = *(const uint4*)(srcp + seg * 8);
    }
}

// ---------------------------------------------------------------------------
// MFMA flash attention (v2 structure, measured 85 us): fixed-max softmax,
// register-prefetch double-buffered K2s/V2s, dedicated per-wave Ps,
// ONE barrier per tile. Qh comes pre-scaled by 1/8.
__global__ __launch_bounds__(256) void attn_mfma(
    const u16* __restrict__ Qh, const u16* __restrict__ K2h, const u16* __restrict__ V2t,
    const float* __restrict__ Mq, const float* __restrict__ Uk, const float* __restrict__ Vk,
    const int* __restrict__ mask, u16* __restrict__ X)
{
    __shared__ u16 K2s[2][64][72];
    __shared__ u16 V2s[2][64][72];
    __shared__ u16 Ps[4][16][72];

    const int tid = threadIdx.x;
    const int wave = tid >> 6, lane = tid & 63;
    const int col = lane & 15, quad = lane >> 4;
    const int b = blockIdx.z, h = blockIdx.y;
    const int q0 = blockIdx.x * 64;
    const size_t hb = ((size_t)(b * NH + h)) * S_LEN * DK;
    const size_t sb = ((size_t)(b * NH + h)) * S_LEN;

    bf16x8 qf0, qf1;
    {
        const u16* qp = Qh + (size_t)(b * S_LEN + q0 + wave * 16 + col) * D_MODEL + h * 64 + quad * 8;
        qf0 = *(const bf16x8*)qp;
        qf1 = *(const bf16x8*)(qp + 32);
    }
    float mqv[4];
    #pragma unroll
    for (int r = 0; r < 4; r++)
        mqv[r] = Mq[sb + q0 + wave * 16 + quad * 4 + r];

    const int srow = tid >> 2, sseg = tid & 3;
    const u16* ksrc = K2h + (size_t)(b * S_LEN + srow) * D_MODEL + h * 64 + sseg * 16;
    const u16* vsrc = V2t + hb + (size_t)srow * S_LEN + sseg * 16;
    const int* mrow = mask + (size_t)b * S_LEN * S_LEN
                    + (size_t)(q0 + wave * 16 + quad * 4) * S_LEN + col;

    uint4 ka = *(const uint4*)(ksrc);
    uint4 kb = *(const uint4*)(ksrc + 8);
    uint4 va = *(const uint4*)(vsrc);
    uint4 vb = *(const uint4*)(vsrc + 8);
    float ku[4], kv[4];
    int mk[4][4];
    #pragma unroll
    for (int nb = 0; nb < 4; nb++) {
        ku[nb] = Uk[sb + nb * 16 + col];
        kv[nb] = Vk[sb + nb * 16 + col];
        #pragma unroll
        for (int r = 0; r < 4; r++) mk[nb][r] = mrow[(size_t)r * S_LEN + nb * 16];
    }

    float psum[4] = {0.f, 0.f, 0.f, 0.f};
    f32x4 o[4];
    #pragma unroll
    for (int nb = 0; nb < 4; nb++) o[nb] = (f32x4){0.f, 0.f, 0.f, 0.f};

    for (int t = 0; t < 16; t++) {
        const int bsel = t & 1;
        *(uint4*)&K2s[bsel][srow][sseg * 16]     = ka;
        *(uint4*)&K2s[bsel][srow][sseg * 16 + 8] = kb;
        *(uint4*)&V2s[bsel][srow][sseg * 16]     = va;
        *(uint4*)&V2s[bsel][srow][sseg * 16 + 8] = vb;
        __syncthreads();  // single barrier per tile

        float kun[4], kvn[4];
        int mkn[4][4];
        if (t < 15) {
            const int k1 = (t + 1) * 64;
            const u16* ks = ksrc + (size_t)k1 * D_MODEL;
            const u16* vs = vsrc + k1;
            ka = *(const uint4*)(ks);
            kb = *(const uint4*)(ks + 8);
            va = *(const uint4*)(vs);
            vb = *(const uint4*)(vs + 8);
            #pragma unroll
            for (int nb = 0; nb < 4; nb++) {
                kun[nb] = Uk[sb + k1 + nb * 16 + col];
                kvn[nb] = Vk[sb + k1 + nb * 16 + col];
                #pragma unroll
                for (int r = 0; r < 4; r++)
                    mkn[nb][r] = mrow[k1 + (size_t)r * S_LEN + nb * 16];
            }
        }

        // ---- QK^T (Q pre-scaled by 1/8) ----
        f32x4 sc[4];
        #pragma unroll
        for (int nb = 0; nb < 4; nb++) {
            bf16x8 b0 = *(const bf16x8*)&K2s[bsel][nb * 16 + col][quad * 8];
            bf16x8 b1 = *(const bf16x8*)&K2s[bsel][nb * 16 + col][32 + quad * 8];
            f32x4 c = (f32x4){0.f, 0.f, 0.f, 0.f};
            c = __builtin_amdgcn_mfma_f32_16x16x32_bf16(qf0, b0, c, 0, 0, 0);
            c = __builtin_amdgcn_mfma_f32_16x16x32_bf16(qf1, b1, c, 0, 0, 0);
            sc[nb] = c;
        }

        // ---- gate, mask, exp (fixed max 0) ----
        #pragma unroll
        for (int nb = 0; nb < 4; nb++) {
            #pragma unroll
            for (int r = 0; r < 4; r++) {
                float g = 1.f / (1.f + __expf(-(mqv[r] * ku[nb] + kv[nb])));
                float sv = sc[nb][r] * g;
                sv = mk[nb][r] ? sv : -30.f;
                float p = __expf(sv);
                psum[r] += p;
                Ps[wave][quad * 4 + r][nb * 16 + col] = f2bf(p);
            }
        }
        __builtin_amdgcn_s_waitcnt(0xc07f);  // lgkmcnt(0) only; prefetch stays in flight
        bf16x8 a0 = *(const bf16x8*)&Ps[wave][col][quad * 8];
        bf16x8 a1 = *(const bf16x8*)&Ps[wave][col][32 + quad * 8];

        // ---- PV ----
        #pragma unroll
        for (int nb = 0; nb < 4; nb++) {
            bf16x8 b0 = *(const bf16x8*)&V2s[bsel][nb * 16 + col][quad * 8];
            bf16x8 b1 = *(const bf16x8*)&V2s[bsel][nb * 16 + col][32 + quad * 8];
            o[nb] = __builtin_amdgcn_mfma_f32_16x16x32_bf16(a0, b0, o[nb], 0, 0, 0);
            o[nb] = __builtin_amdgcn_mfma_f32_16x16x32_bf16(a1, b1, o[nb], 0, 0, 0);
        }

        if (t < 15) {
            #pragma unroll
            for (int nb = 0; nb < 4; nb++) {
                ku[nb] = kun[nb]; kv[nb] = kvn[nb];
                #pragma unroll
                for (int r = 0; r < 4; r++) mk[nb][r] = mkn[nb][r];
            }
        }
    }

    #pragma unroll
    for (int r = 0; r < 4; r++) {
        float t = psum[r];
        t += __shfl_xor(t, 1);
        t += __shfl_xor(t, 2);
        t += __shfl_xor(t, 4);
        t += __shfl_xor(t, 8);
        float inv = 1.f / t;
        u16* xp = X + (size_t)(b * S_LEN + q0 + wave * 16 + quad * 4 + r) * D_MODEL + h * 64 + col;
        #pragma unroll
        for (int nb = 0; nb < 4; nb++)
            xp[nb * 16] = f2bf(o[nb][r] * inv);
    }
}

// ---------------------------------------------------------------------------
// out_gemm: C(f32) = A(bf16) @ WT^T + bias. BK=64 (two 32-pitch panels),
// register-prefetch staging, grid (32,8) XCD-swizzled.
__global__ __launch_bounds__(256) void out_gemm(
    const u16* __restrict__ A, const u16* __restrict__ WT,
    const float* __restrict__ bias, float* __restrict__ C)
{
    __shared__ u16 As[8192];  // 2 panels x [128][32]
    __shared__ u16 Bs[8192];

    const int tid = threadIdx.x;
    const int wave = tid >> 6, lane = tid & 63;
    const int col = lane & 15, quad = lane >> 4;
    const int wr = wave >> 1, wc = wave & 1;
    const int r0 = blockIdx.x * 128, n0 = blockIdx.y * 128;

    const int arow = tid >> 1, ap = tid & 1;
    const u16* asrc = A + (size_t)(r0 + arow) * D_MODEL + ap * 32;
    const u16* bsrc = WT + (size_t)(n0 + arow) * D_MODEL + ap * 32;
    u16* adst = As + ap * 4096 + arow * 32;
    u16* bdst = Bs + ap * 4096 + arow * 32;

    f32x4 acc[4][4];
    #pragma unroll
    for (int i = 0; i < 4; i++)
        #pragma unroll
        for (int j = 0; j < 4; j++)
            acc[i][j] = (f32x4){0.f, 0.f, 0.f, 0.f};

    uint4 au[4], bu[4];
    #pragma unroll
    for (int i = 0; i < 4; i++) au[i] = *(const uint4*)(asrc + i * 8);
    #pragma unroll
    for (int i = 0; i < 4; i++) bu[i] = *(const uint4*)(bsrc + i * 8);

    for (int k0 = 0; k0 < D_MODEL; k0 += 64) {
        if (k0) __syncthreads();
        #pragma unroll
        for (int i = 0; i < 4; i++) *(uint4*)(adst + i * 8) = au[i];
        #pragma unroll
        for (int i = 0; i < 4; i++) *(uint4*)(bdst + i * 8) = bu[i];
        __syncthreads();

        if (k0 + 64 < D_MODEL) {
            const u16* apn = asrc + k0 + 64;
            const u16* bpn = bsrc + k0 + 64;
            #pragma unroll
            for (int i = 0; i < 4; i++) au[i] = *(const uint4*)(apn + i * 8);
            #pragma unroll
            for (int i = 0; i < 4; i++) bu[i] = *(const uint4*)(bpn + i * 8);
        }

        const u16* Abase = As + (wr * 64 + col) * 32 + quad * 8;
        const u16* Bbase = Bs + (wc * 64 + col) * 32 + quad * 8;
        #pragma unroll
        for (int p = 0; p < 2; p++) {
            bf16x8 af[4], bfr[4];
            #pragma unroll
            for (int mi = 0; mi < 4; mi++) af[mi] = *(const bf16x8*)(Abase + p * 4096 + mi * 512);
            #pragma unroll
            for (int ni = 0; ni < 4; ni++) bfr[ni] = *(const bf16x8*)(Bbase + p * 4096 + ni * 512);
            #pragma unroll
            for (int mi = 0; mi < 4; mi++)
                #pragma unroll
                for (int ni = 0; ni < 4; ni++)
                    acc[mi][ni] = __builtin_amdgcn_mfma_f32_16x16x32_bf16(af[mi], bfr[ni], acc[mi][ni], 0, 0, 0);
        }
    }

    #pragma unroll
    for (int mi = 0; mi < 4; mi++)
        #pragma unroll
        for (int ni = 0; ni < 4; ni++) {
            const int gr = r0 + wr * 64 + mi * 16 + quad * 4;
            const int gc = n0 + wc * 64 + ni * 16 + col;
            const float bb = bias[gc];
            #pragma unroll
            for (int r = 0; r < 4; r++)
                C[(size_t)(gr + r) * D_MODEL + gc] = acc[mi][ni][r] + bb;
        }
}

// ---------------------------------------------------------------------------
extern "C" void kernel_launch(void* const* d_in, const int* in_sizes, int n_in,
                              void* d_out, int out_size, void* d_ws, size_t ws_size,
                              hipStream_t stream) {
    (void)in_sizes; (void)n_in; (void)out_size; (void)ws_size;
    const float* query = (const float*)d_in[0];
    const float* key_  = (const float*)d_in[1];
    const float* value = (const float*)d_in[2];
    const int*   mask  = (const int*)d_in[3];
    const float* wq = (const float*)d_in[4];  const float* bq = (const float*)d_in[5];
    const float* wk = (const float*)d_in[6];  const float* bk = (const float*)d_in[7];
    const float* wv = (const float*)d_in[8];  const float* bv = (const float*)d_in[9];
    const float* wo = (const float*)d_in[10]; const float* bo = (const float*)d_in[11];
    const float* spatial_w = (const float*)d_in[12]; const float* spatial_b = (const float*)d_in[13];
    const float* qproj_w   = (const float*)d_in[14]; const float* qproj_b   = (const float*)d_in[15];
    const float* kproj_w   = (const float*)d_in[16]; const float* kproj_b   = (const float*)d_in[17];
    const float* vlin_w    = (const float*)d_in[18]; const float* vlin_b    = (const float*)d_in[19];
    const float* chan_w    = (const float*)d_in[20]; const float* chan_b    = (const float*)d_in[21];
    float* out = (float*)d_out;

    char* ws = (char*)d_ws;
    u16* Qh  = (u16*)ws;                          // 8 MB [B,S,H,DK] bf16 (pre-scaled 1/8)
    u16* K2  = (u16*)(ws + ((size_t)8  << 20));   // 8 MB [B,S,H,DK] bf16
    u16* Xb  = (u16*)(ws + ((size_t)16 << 20));   // 8 MB [B,S,D] bf16 (attn out)
    u16* WT  = (u16*)(ws + ((size_t)24 << 20));   // 8 MB: 4 transposed weights
    u16* V2t = (u16*)(ws + ((size_t)32 << 20));   // 8 MB [B,H,DK,S] bf16
    float* mB = (float*)(ws + ((size_t)40 << 20));
    float* uB = mB + (size_t)BATCH * NH * S_LEN;
    float* vB = uB + (size_t)BATCH * NH * S_LEN;
    const size_t WSZ = (size_t)D_MODEL * D_MODEL;

    cast_wt<<<dim3(16, 16, 4), 256, 0, stream>>>(wq, wk, wv, wo, WT);
    proj_fused<<<dim3(32, 8, 3), 256, 0, stream>>>(query, key_, value,
        WT, WT + WSZ, WT + 2 * WSZ, bq, bk, bv,
        spatial_w, spatial_b, qproj_w, qproj_b, kproj_w, kproj_b,
        vlin_w, vlin_b, chan_w, chan_b,
        Qh, K2, V2t, mB, uB, vB);
    attn_mfma<<<dim3(S_LEN / 64, NH, BATCH), 256, 0, stream>>>(Qh, K2, V2t, mB, uB, vB, mask, Xb);
    out_gemm<<<dim3(32, 8), 256, 0, stream>>>(Xb, WT + 3 * WSZ, bo, out);
}

// Round 9
// 314.269 us; speedup vs baseline: 1.1946x; 1.1946x over previous
//
#include <hip/hip_runtime.h>
#include <math.h>

#define D_MODEL 1024
#define NH 16
#define DK 64
#define S_LEN 1024
#define BATCH 4
#define MROWS (BATCH * S_LEN)  // 4096

typedef short bf16x8 __attribute__((ext_vector_type(8)));
typedef float f32x4 __attribute__((ext_vector_type(4)));
typedef unsigned short u16;

__device__ __forceinline__ float elu1(float x) {
    return x > 0.f ? x : (expf(x) - 1.f);
}

__device__ __forceinline__ u16 f2bf(float f) {
    union { float f; unsigned u; } v; v.f = f;
    unsigned u = v.u;
    return (u16)((u + 0x7fffu + ((u >> 16) & 1u)) >> 16);
}

__device__ __forceinline__ unsigned pack2(float a, float b) {
    union { float f; unsigned u; } ua, ub; ua.f = a; ub.f = b;
    return ((ua.u + 0x8000u) >> 16) | ((ub.u + 0x8000u) & 0xffff0000u);
}

__device__ __forceinline__ void async16(const void* g, void* l) {
    __builtin_amdgcn_global_load_lds(
        (const __attribute__((address_space(1))) unsigned int*)g,
        (__attribute__((address_space(3))) unsigned int*)l,
        16, 0, 0);
}

// ---------------------------------------------------------------------------
// cast_wt: W f32 [k][n] -> WT bf16 [n][k], for the 4 d_model x d_model weights.
__global__ __launch_bounds__(256) void cast_wt(
    const float* __restrict__ wq, const float* __restrict__ wk,
    const float* __restrict__ wv, const float* __restrict__ wo,
    u16* __restrict__ WT)
{
    __shared__ float T[64][65];
    const int z = blockIdx.z;
    const float* W = (z == 0) ? wq : ((z == 1) ? wk : ((z == 2) ? wv : wo));
    u16* O = WT + (size_t)z * D_MODEL * D_MODEL;
    const int tid = threadIdx.x;
    const int k0 = blockIdx.y * 64, n0 = blockIdx.x * 64;
    const int r = tid >> 4, c4 = (tid & 15) * 4;
    #pragma unroll
    for (int p = 0; p < 4; p++) {
        float4 v = *(const float4*)&W[(size_t)(k0 + r + p * 16) * D_MODEL + n0 + c4];
        T[r + p * 16][c4 + 0] = v.x; T[r + p * 16][c4 + 1] = v.y;
        T[r + p * 16][c4 + 2] = v.z; T[r + p * 16][c4 + 3] = v.w;
    }
    __syncthreads();
    #pragma unroll
    for (int p = 0; p < 4; p++) {
        const int i = r + p * 16;
        ushort4 o4;
        o4.x = f2bf(T[c4 + 0][i]); o4.y = f2bf(T[c4 + 1][i]);
        o4.z = f2bf(T[c4 + 2][i]); o4.w = f2bf(T[c4 + 3][i]);
        *(ushort4*)&O[(size_t)(n0 + i) * D_MODEL + k0 + c4] = o4;
    }
}

// ---------------------------------------------------------------------------
// proj_fused v3: 128x64 tile = one head per block. Grid (32,16,3):
// flat%8 = bx%8 -> all 16 head-blocks of a row-strip on one XCD.
// Wave = 32 rows x 64 cols, acc 2x4. BK=32; A f32 reg-prefetch (16 f32/thread),
// B via async16 (no VGPR cost). Phase 2: head 64x64 linear via per-wave
// [16][72] LDS chunks (aliased over dead As/Bs); V-transpose via dead W2t.
// LDS total ~21.5 KB -> ~5-6 blocks/CU.
__global__ __launch_bounds__(256) void proj_fused(
    const float* __restrict__ Xq, const float* __restrict__ Xk, const float* __restrict__ Xv,
    const u16* __restrict__ WTq, const u16* __restrict__ WTk, const u16* __restrict__ WTv,
    const float* __restrict__ bq, const float* __restrict__ bk, const float* __restrict__ bv,
    const float* __restrict__ spatial_w, const float* __restrict__ spatial_b,
    const float* __restrict__ qproj_w, const float* __restrict__ qproj_b,
    const float* __restrict__ kproj_w, const float* __restrict__ kproj_b,
    const float* __restrict__ vlin_w, const float* __restrict__ vlin_b,
    const float* __restrict__ chan_w, const float* __restrict__ chan_b,
    u16* __restrict__ Qh, u16* __restrict__ K2, u16* __restrict__ V2t,
    float* __restrict__ mB, float* __restrict__ uB, float* __restrict__ vB)
{
    // u16 units: As [128][32] = 0..4095 ; Bs [64][32] = 4096..6143 ;
    // W2t [64][72] = 6144..10751. Phase 2: Pchunk = smem + wave*1536 ([16][72]),
    // Tb (V transpose, [64][72]) aliases W2t after its reads are done.
    __shared__ __align__(16) u16 smem[10752];
    __shared__ float auxA[64];
    __shared__ float auxS;

    u16* As = smem;
    u16* Bs = smem + 4096;
    u16* W2t = smem + 6144;

    const int z = blockIdx.z;
    const float* X = (z == 0) ? Xq : ((z == 1) ? Xk : Xv);
    const u16* WT = (z == 0) ? WTq : ((z == 1) ? WTk : WTv);
    const float* B1 = (z == 0) ? bq : ((z == 1) ? bk : bv);
    const float* W2 = (z == 0) ? spatial_w : ((z == 1) ? kproj_w : vlin_w);
    const float* B2 = (z == 0) ? spatial_b : ((z == 1) ? kproj_b : vlin_b);

    const int tid = threadIdx.x;
    const int wave = tid >> 6, lane = tid & 63;
    const int col = lane & 15, quad = lane >> 4;
    const int r0 = blockIdx.x * 128;
    const int hh = blockIdx.y;          // head (one per block)
    const int n0 = hh * 64;

    // ---- stage W2t (transposed bf16) + aux ----
    #pragma unroll
    for (int p = 0; p < 4; p++) {
        int idx = p * 256 + tid;
        int f = idx >> 4, e4 = (idx & 15) * 4;
        float4 w4 = *(const float4*)&W2[f * 64 + e4];
        W2t[(e4 + 0) * 72 + f] = f2bf(w4.x);
        W2t[(e4 + 1) * 72 + f] = f2bf(w4.y);
        W2t[(e4 + 2) * 72 + f] = f2bf(w4.z);
        W2t[(e4 + 3) * 72 + f] = f2bf(w4.w);
    }
    if (z == 0) {
        {
            int row = tid >> 2, part = tid & 3;
            float s = 0.f;
            for (int e = part * 16; e < part * 16 + 16; e++) s += qproj_w[row * 64 + e];
            s += __shfl_xor(s, 1);
            s += __shfl_xor(s, 2);
            if (part == 0) auxA[row] = s * (1.f / 64.f);
        }
        if (tid < 64) {
            float s = qproj_b[tid];
            #pragma unroll
            for (int m = 1; m < 64; m <<= 1) s += __shfl_xor(s, m);
            if (tid == 0) auxS = s * (1.f / 64.f);
        }
    }

    // ---- phase 1: GEMM 128x64, BK=32 ----
    // A: thread -> (row = tid>>1, half = tid&1): 16 f32 -> 16 bf16 per iter
    const int arow = tid >> 1, ahalf = tid & 1;
    const float* aptr = X + (size_t)(r0 + arow) * D_MODEL + ahalf * 16;
    u16* adst = As + arow * 32 + ahalf * 16;

    // B: wave stages rows [wave*16, +16): 1 async16 per iter
    const u16* bp = WT + (size_t)(n0 + wave * 16 + (lane >> 2)) * D_MODEL + (lane & 3) * 8;
    u16* bdst = Bs + wave * 16 * 32;

    f32x4 acc[2][4];
    #pragma unroll
    for (int i = 0; i < 2; i++)
        #pragma unroll
        for (int j = 0; j < 4; j++)
            acc[i][j] = (f32x4){0.f, 0.f, 0.f, 0.f};

    float4 fr[4];
    #pragma unroll
    for (int i = 0; i < 4; i++) fr[i] = *(const float4*)(aptr + i * 4);

    for (int k0 = 0; k0 < D_MODEL; k0 += 32) {
        if (k0) __syncthreads();
        async16(bp + k0, bdst);
        {
            uint4 q0, q1;
            q0.x = pack2(fr[0].x, fr[0].y); q0.y = pack2(fr[0].z, fr[0].w);
            q0.z = pack2(fr[1].x, fr[1].y); q0.w = pack2(fr[1].z, fr[1].w);
            q1.x = pack2(fr[2].x, fr[2].y); q1.y = pack2(fr[2].z, fr[2].w);
            q1.z = pack2(fr[3].x, fr[3].y); q1.w = pack2(fr[3].z, fr[3].w);
            *(uint4*)adst = q0;
            *(uint4*)(adst + 8) = q1;
        }
        if (k0 + 32 < D_MODEL) {
            const float* ap = aptr + k0 + 32;
            #pragma unroll
            for (int i = 0; i < 4; i++) fr[i] = *(const float4*)(ap + i * 4);
        }
        __syncthreads();
        const u16* Abase = As + (wave * 32 + col) * 32 + quad * 8;
        const u16* Bbase = Bs + col * 32 + quad * 8;
        bf16x8 af[2], bfr[4];
        #pragma unroll
        for (int mi = 0; mi < 2; mi++) af[mi] = *(const bf16x8*)(Abase + mi * 512);
        #pragma unroll
        for (int ni = 0; ni < 4; ni++) bfr[ni] = *(const bf16x8*)(Bbase + ni * 512);
        #pragma unroll
        for (int mi = 0; mi < 2; mi++)
            #pragma unroll
            for (int ni = 0; ni < 4; ni++)
                acc[mi][ni] = __builtin_amdgcn_mfma_f32_16x16x32_bf16(af[mi], bfr[ni], acc[mi][ni], 0, 0, 0);
    }

    // ---- phase 2: epilogue ----
    float b1v[4];
    #pragma unroll
    for (int ni = 0; ni < 4; ni++) b1v[ni] = B1[n0 + ni * 16 + col];

    const int rbase = r0 + wave * 32;          // wave's first row
    const int b = r0 >> 10;                     // 128-row tile never crosses batch
    const int s0 = (r0 & 1023) + wave * 32;
    const size_t svecbase = ((size_t)b * NH + hh) * S_LEN;

    if (z == 1) {
        float cw[4], cb[4];
        #pragma unroll
        for (int ni = 0; ni < 4; ni++) { cw[ni] = chan_w[ni * 16 + col]; cb[ni] = chan_b[ni * 16 + col]; }
        #pragma unroll
        for (int mi = 0; mi < 2; mi++)
            #pragma unroll
            for (int r = 0; r < 4; r++) {
                float su = 0.f, sv = 0.f;
                #pragma unroll
                for (int ni = 0; ni < 4; ni++) {
                    float p = acc[mi][ni][r] + b1v[ni];
                    su += p * cw[ni];
                    sv += p * cb[ni];
                }
                su += __shfl_xor(su, 1); su += __shfl_xor(su, 2);
                su += __shfl_xor(su, 4); su += __shfl_xor(su, 8);
                sv += __shfl_xor(sv, 1); sv += __shfl_xor(sv, 2);
                sv += __shfl_xor(sv, 4); sv += __shfl_xor(sv, 8);
                if (col == 0) {
                    const size_t idx = svecbase + s0 + mi * 16 + quad * 4 + r;
                    uB[idx] = su;
                    vB[idx] = sv;
                }
            }
    }

    __syncthreads();  // phase-1 As/Bs reads done; safe to alias Pchunk

    // head linear via 16-row chunks: per wave Pchunk [16][72] in dead As/Bs
    u16* Pchunk = smem + wave * 1536;
    bf16x8 bf2r[4][2];
    #pragma unroll
    for (int ni = 0; ni < 4; ni++) {
        bf2r[ni][0] = *(const bf16x8*)&W2t[(ni * 16 + col) * 72 + quad * 8];
        bf2r[ni][1] = *(const bf16x8*)&W2t[(ni * 16 + col) * 72 + 32 + quad * 8];
    }
    float qs[2][4][4];
    #pragma unroll
    for (int mi = 0; mi < 2; mi++) {
        #pragma unroll
        for (int ni = 0; ni < 4; ni++)
            #pragma unroll
            for (int r = 0; r < 4; r++)
                Pchunk[(quad * 4 + r) * 72 + ni * 16 + col] = f2bf(acc[mi][ni][r] + b1v[ni]);
        __builtin_amdgcn_s_waitcnt(0xc07f);  // lgkmcnt(0): wave-local chunk visible
        bf16x8 a0 = *(const bf16x8*)&Pchunk[col * 72 + quad * 8];
        bf16x8 a1 = *(const bf16x8*)&Pchunk[col * 72 + 32 + quad * 8];
        __builtin_amdgcn_s_waitcnt(0xc07f);  // reads done before mi+1 overwrites
        #pragma unroll
        for (int ni = 0; ni < 4; ni++) {
            f32x4 c = (f32x4){0.f, 0.f, 0.f, 0.f};
            c = __builtin_amdgcn_mfma_f32_16x16x32_bf16(a0, bf2r[ni][0], c, 0, 0, 0);
            c = __builtin_amdgcn_mfma_f32_16x16x32_bf16(a1, bf2r[ni][1], c, 0, 0, 0);
            const float bb = B2[ni * 16 + col];
            #pragma unroll
            for (int r = 0; r < 4; r++) qs[mi][ni][r] = elu1(c[r] + bb);
        }
    }

    if (z == 0) {
        float aw[4];
        #pragma unroll
        for (int ni = 0; ni < 4; ni++) aw[ni] = auxA[ni * 16 + col];
        #pragma unroll
        for (int mi = 0; mi < 2; mi++)
            #pragma unroll
            for (int r = 0; r < 4; r++) {
                float pm = 0.f;
                #pragma unroll
                for (int ni = 0; ni < 4; ni++) pm += qs[mi][ni][r] * aw[ni];
                pm += __shfl_xor(pm, 1); pm += __shfl_xor(pm, 2);
                pm += __shfl_xor(pm, 4); pm += __shfl_xor(pm, 8);
                if (col == 0)
                    mB[svecbase + s0 + mi * 16 + quad * 4 + r] = pm + auxS;
            }
        #pragma unroll
        for (int mi = 0; mi < 2; mi++)
            #pragma unroll
            for (int ni = 0; ni < 4; ni++)
                #pragma unroll
                for (int r = 0; r < 4; r++)
                    Qh[(size_t)(rbase + mi * 16 + quad * 4 + r) * D_MODEL
                       + n0 + ni * 16 + col] = f2bf(qs[mi][ni][r] * 0.125f);
    } else if (z == 1) {
        #pragma unroll
        for (int mi = 0; mi < 2; mi++)
            #pragma unroll
            for (int ni = 0; ni < 4; ni++)
                #pragma unroll
                for (int r = 0; r < 4; r++)
                    K2[(size_t)(rbase + mi * 16 + quad * 4 + r) * D_MODEL
                       + n0 + ni * 16 + col] = f2bf(qs[mi][ni][r]);
    } else {
        // V: block-level transpose via Tb (= W2t region, [64][72]), 2 passes of
        // 64 s-rows each. All z==2 blocks take this path (uniform barriers).
        u16* Tb = W2t;
        __syncthreads();  // all W2t reads (bf2r) complete before overwrite
        #pragma unroll
        for (int p = 0; p < 2; p++) {
            if ((wave >> 1) == p) {
                const int sloc = (wave & 1) * 32;  // s offset within pass
                #pragma unroll
                for (int mi = 0; mi < 2; mi++)
                    #pragma unroll
                    for (int ni = 0; ni < 4; ni++)
                        #pragma unroll
                        for (int r = 0; r < 4; r++)
                            Tb[(ni * 16 + col) * 72 + sloc + mi * 16 + quad * 4 + r] =
                                f2bf(qs[mi][ni][r]);
            }
            __syncthreads();
            {
                const int d = tid >> 2, seg = tid & 3;
                u16* dst = V2t + (((size_t)b * NH + hh) * DK + d) * S_LEN
                         + (r0 & 1023) + p * 64 + seg * 16;
                *(uint4*)dst = *(const uint4*)&Tb[d * 72 + seg * 16];
                *(uint4*)(dst + 8) = *(const uint4*)&Tb[d * 72 + seg * 16 + 8];
            }
            if (p == 0) __syncthreads();
        }
    }
}

// ---------------------------------------------------------------------------
// MFMA flash attention (v2 structure, measured 85 us): fixed-max softmax,
// register-prefetch double-buffered K2s/V2s, dedicated per-wave Ps,
// ONE barrier per tile. Qh comes pre-scaled by 1/8.
__global__ __launch_bounds__(256) void attn_mfma(
    const u16* __restrict__ Qh, const u16* __restrict__ K2h, const u16* __restrict__ V2t,
    const float* __restrict__ Mq, const float* __restrict__ Uk, const float* __restrict__ Vk,
    const int* __restrict__ mask, u16* __restrict__ X)
{
    __shared__ u16 K2s[2][64][72];
    __shared__ u16 V2s[2][64][72];
    __shared__ u16 Ps[4][16][72];

    const int tid = threadIdx.x;
    const int wave = tid >> 6, lane = tid & 63;
    const int col = lane & 15, quad = lane >> 4;
    const int b = blockIdx.z, h = blockIdx.y;
    const int q0 = blockIdx.x * 64;
    const size_t hb = ((size_t)(b * NH + h)) * S_LEN * DK;
    const size_t sb = ((size_t)(b * NH + h)) * S_LEN;

    bf16x8 qf0, qf1;
    {
        const u16* qp = Qh + (size_t)(b * S_LEN + q0 + wave * 16 + col) * D_MODEL + h * 64 + quad * 8;
        qf0 = *(const bf16x8*)qp;
        qf1 = *(const bf16x8*)(qp + 32);
    }
    float mqv[4];
    #pragma unroll
    for (int r = 0; r < 4; r++)
        mqv[r] = Mq[sb + q0 + wave * 16 + quad * 4 + r];

    const int srow = tid >> 2, sseg = tid & 3;
    const u16* ksrc = K2h + (size_t)(b * S_LEN + srow) * D_MODEL + h * 64 + sseg * 16;
    const u16* vsrc = V2t + hb + (size_t)srow * S_LEN + sseg * 16;
    const int* mrow = mask + (size_t)b * S_LEN * S_LEN
                    + (size_t)(q0 + wave * 16 + quad * 4) * S_LEN + col;

    uint4 ka = *(const uint4*)(ksrc);
    uint4 kb = *(const uint4*)(ksrc + 8);
    uint4 va = *(const uint4*)(vsrc);
    uint4 vb = *(const uint4*)(vsrc + 8);
    float ku[4], kv[4];
    int mk[4][4];
    #pragma unroll
    for (int nb = 0; nb < 4; nb++) {
        ku[nb] = Uk[sb + nb * 16 + col];
        kv[nb] = Vk[sb + nb * 16 + col];
        #pragma unroll
        for (int r = 0; r < 4; r++) mk[nb][r] = mrow[(size_t)r * S_LEN + nb * 16];
    }

    float psum[4] = {0.f, 0.f, 0.f, 0.f};
    f32x4 o[4];
    #pragma unroll
    for (int nb = 0; nb < 4; nb++) o[nb] = (f32x4){0.f, 0.f, 0.f, 0.f};

    for (int t = 0; t < 16; t++) {
        const int bsel = t & 1;
        *(uint4*)&K2s[bsel][srow][sseg * 16]     = ka;
        *(uint4*)&K2s[bsel][srow][sseg * 16 + 8] = kb;
        *(uint4*)&V2s[bsel][srow][sseg * 16]     = va;
        *(uint4*)&V2s[bsel][srow][sseg * 16 + 8] = vb;
        __syncthreads();  // single barrier per tile

        float kun[4], kvn[4];
        int mkn[4][4];
        if (t < 15) {
            const int k1 = (t + 1) * 64;
            const u16* ks = ksrc + (size_t)k1 * D_MODEL;
            const u16* vs = vsrc + k1;
            ka = *(const uint4*)(ks);
            kb = *(const uint4*)(ks + 8);
            va = *(const uint4*)(vs);
            vb = *(const uint4*)(vs + 8);
            #pragma unroll
            for (int nb = 0; nb < 4; nb++) {
                kun[nb] = Uk[sb + k1 + nb * 16 + col];
                kvn[nb] = Vk[sb + k1 + nb * 16 + col];
                #pragma unroll
                for (int r = 0; r < 4; r++)
                    mkn[nb][r] = mrow[k1 + (size_t)r * S_LEN + nb * 16];
            }
        }

        // ---- QK^T (Q pre-scaled by 1/8) ----
        f32x4 sc[4];
        #pragma unroll
        for (int nb = 0; nb < 4; nb++) {
            bf16x8 b0 = *(const bf16x8*)&K2s[bsel][nb * 16 + col][quad * 8];
            bf16x8 b1 = *(const bf16x8*)&K2s[bsel][nb * 16 + col][32 + quad * 8];
            f32x4 c = (f32x4){0.f, 0.f, 0.f, 0.f};
            c = __builtin_amdgcn_mfma_f32_16x16x32_bf16(qf0, b0, c, 0, 0, 0);
            c = __builtin_amdgcn_mfma_f32_16x16x32_bf16(qf1, b1, c, 0, 0, 0);
            sc[nb] = c;
        }

        // ---- gate, mask, exp (fixed max 0) ----
        #pragma unroll
        for (int nb = 0; nb < 4; nb++) {
            #pragma unroll
            for (int r = 0; r < 4; r++) {
                float g = 1.f / (1.f + __expf(-(mqv[r] * ku[nb] + kv[nb])));
                float sv = sc[nb][r] * g;
                sv = mk[nb][r] ? sv : -30.f;
                float p = __expf(sv);
                psum[r] += p;
                Ps[wave][quad * 4 + r][nb * 16 + col] = f2bf(p);
            }
        }
        __builtin_amdgcn_s_waitcnt(0xc07f);  // lgkmcnt(0) only; prefetch stays in flight
        bf16x8 a0 = *(const bf16x8*)&Ps[wave][col][quad * 8];
        bf16x8 a1 = *(const bf16x8*)&Ps[wave][col][32 + quad * 8];

        // ---- PV ----
        #pragma unroll
        for (int nb = 0; nb < 4; nb++) {
            bf16x8 b0 = *(const bf16x8*)&V2s[bsel][nb * 16 + col][quad * 8];
            bf16x8 b1 = *(const bf16x8*)&V2s[bsel][nb * 16 + col][32 + quad * 8];
            o[nb] = __builtin_amdgcn_mfma_f32_16x16x32_bf16(a0, b0, o[nb], 0, 0, 0);
            o[nb] = __builtin_amdgcn_mfma_f32_16x16x32_bf16(a1, b1, o[nb], 0, 0, 0);
        }

        if (t < 15) {
            #pragma unroll
            for (int nb = 0; nb < 4; nb++) {
                ku[nb] = kun[nb]; kv[nb] = kvn[nb];
                #pragma unroll
                for (int r = 0; r < 4; r++) mk[nb][r] = mkn[nb][r];
            }
        }
    }

    #pragma unroll
    for (int r = 0; r < 4; r++) {
        float t = psum[r];
        t += __shfl_xor(t, 1);
        t += __shfl_xor(t, 2);
        t += __shfl_xor(t, 4);
        t += __shfl_xor(t, 8);
        float inv = 1.f / t;
        u16* xp = X + (size_t)(b * S_LEN + q0 + wave * 16 + quad * 4 + r) * D_MODEL + h * 64 + col;
        #pragma unroll
        for (int nb = 0; nb < 4; nb++)
            xp[nb * 16] = f2bf(o[nb][r] * inv);
    }
}

// ---------------------------------------------------------------------------
// out_gemm: C(f32) = A(bf16) @ WT^T + bias. 64x64 tiles, grid (64,16) = 1024
// blocks (~4/CU), async16 staging, BK=32, wave = 16x64, acc[1][4].
__global__ __launch_bounds__(256) void out_gemm(
    const u16* __restrict__ A, const u16* __restrict__ WT,
    const float* __restrict__ bias, float* __restrict__ C)
{
    __shared__ u16 As[64 * 32];
    __shared__ u16 Bs[64 * 32];

    const int tid = threadIdx.x;
    const int wave = tid >> 6, lane = tid & 63;
    const int col = lane & 15, quad = lane >> 4;
    const int r0 = blockIdx.x * 64, n0 = blockIdx.y * 64;

    // wave stages 16 rows of A and of B per iter (1 async16 each)
    const u16* ap = A + (size_t)(r0 + wave * 16 + (lane >> 2)) * D_MODEL + (lane & 3) * 8;
    const u16* bp = WT + (size_t)(n0 + wave * 16 + (lane >> 2)) * D_MODEL + (lane & 3) * 8;
    u16* adst = As + wave * 16 * 32;
    u16* bdst = Bs + wave * 16 * 32;

    f32x4 acc[4];
    #pragma unroll
    for (int j = 0; j < 4; j++) acc[j] = (f32x4){0.f, 0.f, 0.f, 0.f};

    for (int k0 = 0; k0 < D_MODEL; k0 += 32) {
        if (k0) __syncthreads();
        async16(ap + k0, adst);
        async16(bp + k0, bdst);
        __syncthreads();
        const u16* Ab = As + (wave * 16 + col) * 32 + quad * 8;
        const u16* Bb = Bs + col * 32 + quad * 8;
        bf16x8 af = *(const bf16x8*)Ab;
        bf16x8 bfr[4];
        #pragma unroll
        for (int ni = 0; ni < 4; ni++) bfr[ni] = *(const bf16x8*)(Bb + ni * 512);
        #pragma unroll
        for (int ni = 0; ni < 4; ni++)
            acc[ni] = __builtin_amdgcn_mfma_f32_16x16x32_bf16(af, bfr[ni], acc[ni], 0, 0, 0);
    }

    #pragma unroll
    for (int ni = 0; ni < 4; ni++) {
        const int gr = r0 + wave * 16 + quad * 4;
        const int gc = n0 + ni * 16 + col;
        const float bb = bias[gc];
        #pragma unroll
        for (int r = 0; r < 4; r++)
            C[(size_t)(gr + r) * D_MODEL + gc] = acc[ni][r] + bb;
    }
}

// ---------------------------------------------------------------------------
extern "C" void kernel_launch(void* const* d_in, const int* in_sizes, int n_in,
                              void* d_out, int out_size, void* d_ws, size_t ws_size,
                              hipStream_t stream) {
    (void)in_sizes; (void)n_in; (void)out_size; (void)ws_size;
    const float* query = (const float*)d_in[0];
    const float* key_  = (const float*)d_in[1];
    const float* value = (const float*)d_in[2];
    const int*   mask  = (const int*)d_in[3];
    const float* wq = (const float*)d_in[4];  const float* bq = (const float*)d_in[5];
    const float* wk = (const float*)d_in[6];  const float* bk = (const float*)d_in[7];
    const float* wv = (const float*)d_in[8];  const float* bv = (const float*)d_in[9];
    const float* wo = (const float*)d_in[10]; const float* bo = (const float*)d_in[11];
    const float* spatial_w = (const float*)d_in[12]; const float* spatial_b = (const float*)d_in[13];
    const float* qproj_w   = (const float*)d_in[14]; const float* qproj_b   = (const float*)d_in[15];
    const float* kproj_w   = (const float*)d_in[16]; const float* kproj_b   = (const float*)d_in[17];
    const float* vlin_w    = (const float*)d_in[18]; const float* vlin_b    = (const float*)d_in[19];
    const float* chan_w    = (const float*)d_in[20]; const float* chan_b    = (const float*)d_in[21];
    float* out = (float*)d_out;

    char* ws = (char*)d_ws;
    u16* Qh  = (u16*)ws;                          // 8 MB [B,S,H,DK] bf16 (pre-scaled 1/8)
    u16* K2  = (u16*)(ws + ((size_t)8  << 20));   // 8 MB [B,S,H,DK] bf16
    u16* Xb  = (u16*)(ws + ((size_t)16 << 20));   // 8 MB [B,S,D] bf16 (attn out)
    u16* WT  = (u16*)(ws + ((size_t)24 << 20));   // 8 MB: 4 transposed weights
    u16* V2t = (u16*)(ws + ((size_t)32 << 20));   // 8 MB [B,H,DK,S] bf16
    float* mB = (float*)(ws + ((size_t)40 << 20));
    float* uB = mB + (size_t)BATCH * NH * S_LEN;
    float* vB = uB + (size_t)BATCH * NH * S_LEN;
    const size_t WSZ = (size_t)D_MODEL * D_MODEL;

    cast_wt<<<dim3(16, 16, 4), 256, 0, stream>>>(wq, wk, wv, wo, WT);
    proj_fused<<<dim3(32, 16, 3), 256, 0, stream>>>(query, key_, value,
        WT, WT + WSZ, WT + 2 * WSZ, bq, bk, bv,
        spatial_w, spatial_b, qproj_w, qproj_b, kproj_w, kproj_b,
        vlin_w, vlin_b, chan_w, chan_b,
        Qh, K2, V2t, mB, uB, vB);
    attn_mfma<<<dim3(S_LEN / 64, NH, BATCH), 256, 0, stream>>>(Qh, K2, V2t, mB, uB, vB, mask, Xb);
    out_gemm<<<dim3(64, 16), 256, 0, stream>>>(Xb, WT + 3 * WSZ, bo, out);
}